// Round 1
// baseline (290788.257 us; speedup 1.0000x reference)
//
#include <hip/hip_runtime.h>
#include <cstddef>

#define T_STEPS 4096

// ---- ws layout (32-bit word offsets) ----
#define OFF_FLAGS_E 0          // 1024 u32 (flag of wg i at [i*4])
#define OFF_FLAGS_D 1024       // 1024 u32
#define OFF_HBUF_E  2048       // 3*3072 f32  [slot][ e1 h (2048) | e2 h (1024) ]
#define OFF_HBUF_D  11264      // 3*3072 f32  [slot][ d1 h (1024) | d2 h (2048) ]
#define OFF_XG4     20480      // 3*6144 f32  d2 input gates, mod-3 slots
#define OFF_XGD1    38912      // 3072 f32    d1 constant input gates (incl bih)
#define OFF_PART    41984      // 128*4096 f32 per-wg output partials
#define INIT_WORDS  38912

#define DEV __device__ __forceinline__

DEV float sigm(float v){ return __fdividef(1.f, 1.f + __expf(-v)); }
DEV float tanhx(float v){ float e = __expf(2.f*v); return 1.f - __fdividef(2.f, e + 1.f); }

DEV float wred(float v){
  #pragma unroll
  for (int m = 32; m; m >>= 1) v += __shfl_xor(v, m, 64);
  return v;  // full sum in all 64 lanes
}

DEV void ld32(const float* __restrict__ p, float* d){
  const float4* q = (const float4*)p;
  #pragma unroll
  for (int i=0;i<8;++i){ float4 v = q[i]; d[4*i]=v.x; d[4*i+1]=v.y; d[4*i+2]=v.z; d[4*i+3]=v.w; }
}
DEV void ld16(const float* __restrict__ p, float* d){
  const float4* q = (const float4*)p;
  #pragma unroll
  for (int i=0;i<4;++i){ float4 v = q[i]; d[4*i]=v.x; d[4*i+1]=v.y; d[4*i+2]=v.z; d[4*i+3]=v.w; }
}

// Distributed 256-wg barrier: own-flag release store, poll all flags (agent scope).
DEV void gbar(unsigned* flags, int wg, unsigned target, int tid){
  __threadfence();                  // release: make this wg's h stores visible device-wide
  __syncthreads();
  if (tid == 0)
    __hip_atomic_store(&flags[wg*4], target, __ATOMIC_RELAXED, __HIP_MEMORY_SCOPE_AGENT);
  if (tid < 64){                    // wave 0 polls; lane l covers wgs l, l+64, l+128, l+192
    bool ok;
    do {
      ok = true;
      #pragma unroll
      for (int j=0;j<4;++j){
        unsigned v = __hip_atomic_load(&flags[(tid + 64*j)*4], __ATOMIC_RELAXED, __HIP_MEMORY_SCOPE_AGENT);
        ok = ok && (v >= target);
      }
    } while (!__all(ok));
  }
  __syncthreads();                  // release waiting waves only after poll success
  __threadfence();                  // acquire: invalidate L1/L2 so h reads are fresh
}

__global__ void init_kernel(unsigned* ws){
  const int i = blockIdx.x*blockDim.x + threadIdx.x;
  if (i < INIT_WORDS) ws[i] = 0u;
}

// ================= ENCODER: e1 (128 wgs) + e2 lag-1 (128 wgs) =================
__global__ __launch_bounds__(256, 1) void enc_kernel(
    const float* __restrict__ x,
    const float* __restrict__ e1_Wih, const float* __restrict__ e1_Whh,
    const float* __restrict__ e1_bih, const float* __restrict__ e1_bhh,
    const float* __restrict__ e2_Wih, const float* __restrict__ e2_Whh,
    const float* __restrict__ e2_bih, const float* __restrict__ e2_bhh,
    float* ws)
{
  const int wg = blockIdx.x, tid = threadIdx.x;
  const int wave = tid >> 6, lane = tid & 63;
  float* hbuf = ws + OFF_HBUF_E;
  unsigned* flags = (unsigned*)ws + OFF_FLAGS_E;

  __shared__ float sW[4][12], sBi[4][12], sBh[4][12];

  if (wg < 128){
    // ---- role A: e1 (H=2048). wave owns i0..i0+3; lane owns 32 cols. ----
    const int gw = wg*4 + wave;          // 0..511
    const int i0 = gw*4;
    const int cb = lane*32;
    float w[3][4][32];                   // 384 VGPRs, resident for all 4096 steps
    #pragma unroll
    for (int g=0; g<3; ++g)
      #pragma unroll
      for (int j=0; j<4; ++j)
        ld32(e1_Whh + (size_t)(g*2048 + i0 + j)*2048 + cb, w[g][j]);
    if (lane < 12){
      const int g = lane >> 2, j = lane & 3;
      const int row = g*2048 + i0 + j;
      sW[wave][lane]  = e1_Wih[row];
      sBi[wave][lane] = e1_bih[row];
      sBh[wave][lane] = e1_bhh[row];
    }
    __syncthreads();
    for (int s=0; s<=T_STEPS; ++s){
      if (s < T_STEPS){
        const int t = s;
        const float* hp = hbuf + ((t+2)%3)*3072;
        float*       hw = hbuf + (t%3)*3072;
        float h[32]; ld32(hp + cb, h);
        float hpv[4];
        #pragma unroll
        for (int j=0;j<4;++j) hpv[j] = hp[i0+j];
        const float xt = x[t];
        float acc[3][4];
        #pragma unroll
        for (int g=0; g<3; ++g)
          #pragma unroll
          for (int j=0; j<4; ++j){
            float a = 0.f;
            #pragma unroll
            for (int k=0; k<32; ++k) a = __fmaf_rn(w[g][j][k], h[k], a);
            acc[g][j] = a;
          }
        #pragma unroll
        for (int j=0; j<4; ++j){
          const float hr = wred(acc[0][j]);
          const float hz = wred(acc[1][j]);
          const float hn = wred(acc[2][j]);
          const float r = sigm (__fmaf_rn(xt, sW[wave][j],    sBi[wave][j])    + hr + sBh[wave][j]);
          const float z = sigm (__fmaf_rn(xt, sW[wave][4+j],  sBi[wave][4+j])  + hz + sBh[wave][4+j]);
          const float n = tanhx(__fmaf_rn(xt, sW[wave][8+j],  sBi[wave][8+j])  + r*(hn + sBh[wave][8+j]));
          const float hnew = (1.f - z)*n + z*hpv[j];
          if (lane == 0) hw[i0+j] = hnew;
        }
      }
      gbar(flags, wg, (unsigned)(s+1), tid);
    }
  } else {
    // ---- role B: e2 (H=1024, K_in=2048) lag-1. wave owns i0..i0+1. ----
    const int gw = (wg-128)*4 + wave;    // 0..511
    const int i0 = gw*2;
    const int cb32 = lane*32, cb16 = lane*16;
    float wih[3][2][32], whh[3][2][16];  // 288 VGPRs
    #pragma unroll
    for (int g=0; g<3; ++g)
      #pragma unroll
      for (int j=0; j<2; ++j){
        ld32(e2_Wih + (size_t)(g*1024 + i0 + j)*2048 + cb32, wih[g][j]);
        ld16(e2_Whh + (size_t)(g*1024 + i0 + j)*1024 + cb16, whh[g][j]);
      }
    if (lane < 6){
      const int g = lane >> 1, j = lane & 1;
      const int row = g*1024 + i0 + j;
      sBi[wave][lane] = e2_bih[row];
      sBh[wave][lane] = e2_bhh[row];
    }
    __syncthreads();
    for (int s=0; s<=T_STEPS; ++s){
      if (s >= 1){
        const int t = s-1;
        const float* yp = hbuf + (t%3)*3072;            // ys1[t] (e1 section)
        const float* hp = hbuf + ((t+2)%3)*3072 + 2048; // own h_{t-1}
        float*       hw = hbuf + (t%3)*3072 + 2048;
        float y[32]; ld32(yp + cb32, y);
        float h[16]; ld16(hp + cb16, h);
        float hpv[2];
        #pragma unroll
        for (int j=0;j<2;++j) hpv[j] = hp[i0+j];
        #pragma unroll
        for (int j=0; j<2; ++j){
          float ar=0.f, az=0.f, axn=0.f, ahn=0.f;
          #pragma unroll
          for (int k=0;k<32;++k){
            ar  = __fmaf_rn(wih[0][j][k], y[k], ar);
            az  = __fmaf_rn(wih[1][j][k], y[k], az);
            axn = __fmaf_rn(wih[2][j][k], y[k], axn);
          }
          #pragma unroll
          for (int k=0;k<16;++k){
            ar  = __fmaf_rn(whh[0][j][k], h[k], ar);
            az  = __fmaf_rn(whh[1][j][k], h[k], az);
            ahn = __fmaf_rn(whh[2][j][k], h[k], ahn);
          }
          const float arr = wred(ar), azr = wred(az), axnr = wred(axn), ahnr = wred(ahn);
          const float r = sigm (arr + sBi[wave][j]   + sBh[wave][j]);
          const float z = sigm (azr + sBi[wave][2+j] + sBh[wave][2+j]);
          const float n = tanhx(axnr + sBi[wave][4+j] + r*(ahnr + sBh[wave][4+j]));
          const float hnew = (1.f - z)*n + z*hpv[j];
          if (lane == 0) hw[i0+j] = hnew;
        }
      }
      gbar(flags, wg, (unsigned)(s+1), tid);
    }
  }
}

// xgd1[row] = d1_Wih[row,:] . hT + d1_bih[row]   (hT = e2 h at t=4095, slot 4095%3==0)
__global__ void xgd1_kernel(const float* __restrict__ d1_Wih,
                            const float* __restrict__ d1_bih, float* ws){
  const int gw = blockIdx.x*4 + (threadIdx.x >> 6);  // row 0..3071
  const int lane = threadIdx.x & 63;
  const float* hT = ws + OFF_HBUF_E + 2048;          // slot 0, e2 section
  float h[16]; ld16(hT + lane*16, h);
  float wv[16]; ld16(d1_Wih + (size_t)gw*1024 + lane*16, wv);
  float a = 0.f;
  #pragma unroll
  for (int k=0;k<16;++k) a = __fmaf_rn(wv[k], h[k], a);
  a = wred(a);
  if (lane == 0) ws[OFF_XGD1 + gw] = a + d1_bih[gw];
}

// ====== DECODER: d1 (32 wgs) + d2-input GEMV lag-1 (96 wgs) + d2 lag-2 (128 wgs) ======
__global__ __launch_bounds__(256, 1) void dec_kernel(
    const float* __restrict__ d1_Whh, const float* __restrict__ d1_bhh,
    const float* __restrict__ d2_Wih, const float* __restrict__ d2_Whh,
    const float* __restrict__ d2_bih, const float* __restrict__ d2_bhh,
    const float* __restrict__ out_W,
    float* ws)
{
  const int wg = blockIdx.x, tid = threadIdx.x;
  const int wave = tid >> 6, lane = tid & 63;
  float* hbuf = ws + OFF_HBUF_D;
  float* xg4  = ws + OFF_XG4;
  unsigned* flags = (unsigned*)ws + OFF_FLAGS_D;
  __shared__ float sPS[4];

  if (wg < 32){
    // ---- d1 (H=1024), constant input gates. wave owns i0..i0+7. ----
    const int gw = wg*4 + wave;       // 0..127
    const int i0 = gw*8;
    const int cb = lane*16;
    float w[3][8][16];                // 384 VGPRs
    #pragma unroll
    for (int g=0; g<3; ++g)
      #pragma unroll
      for (int j=0; j<8; ++j)
        ld16(d1_Whh + (size_t)(g*1024 + i0 + j)*1024 + cb, w[g][j]);
    float cr[8], cz[8], cxn[8], cbn[8];
    const float* xgc = ws + OFF_XGD1;
    #pragma unroll
    for (int j=0; j<8; ++j){
      cr[j]  = xgc[i0+j]      + d1_bhh[i0+j];
      cz[j]  = xgc[1024+i0+j] + d1_bhh[1024+i0+j];
      cxn[j] = xgc[2048+i0+j];
      cbn[j] = d1_bhh[2048+i0+j];
    }
    for (int s=0; s<=T_STEPS+1; ++s){
      if (s < T_STEPS){
        const int t = s;
        const float* hp = hbuf + ((t+2)%3)*3072;
        float*       hw = hbuf + (t%3)*3072;
        float h[16]; ld16(hp + cb, h);
        #pragma unroll
        for (int j=0; j<8; ++j){
          float a0=0.f, a1=0.f, a2=0.f;
          #pragma unroll
          for (int k=0;k<16;++k){
            a0 = __fmaf_rn(w[0][j][k], h[k], a0);
            a1 = __fmaf_rn(w[1][j][k], h[k], a1);
            a2 = __fmaf_rn(w[2][j][k], h[k], a2);
          }
          const float hr = wred(a0), hz = wred(a1), hn = wred(a2);
          const float r = sigm (cr[j] + hr);
          const float z = sigm (cz[j] + hz);
          const float n = tanhx(cxn[j] + r*(hn + cbn[j]));
          const float hnew = (1.f - z)*n + z*hp[i0+j];
          if (lane == 0) hw[i0+j] = hnew;
        }
      }
      gbar(flags, wg, (unsigned)(s+1), tid);
    }
  } else if (wg < 128){
    // ---- d2 input GEMV: xg4[t] = d2_Wih @ ys2[t] + bih, lag-1. wave owns 16 rows. ----
    const int gw = (wg-32)*4 + wave;   // 0..383
    const int r0 = gw*16;
    const int cb = lane*16;
    float w[16][16];                   // 256 VGPRs
    #pragma unroll
    for (int r=0; r<16; ++r)
      ld16(d2_Wih + (size_t)(r0 + r)*1024 + cb, w[r]);
    float bv[16];
    #pragma unroll
    for (int r=0; r<16; ++r) bv[r] = d2_bih[r0+r];
    for (int s=0; s<=T_STEPS+1; ++s){
      if (s >= 1 && s <= T_STEPS){
        const int t = s-1;
        const float* yp = hbuf + (t%3)*3072;   // ys2[t] (d1 section)
        float*       xw = xg4 + (t%3)*6144;
        float y[16]; ld16(yp + cb, y);
        #pragma unroll
        for (int r=0; r<16; ++r){
          float a = 0.f;
          #pragma unroll
          for (int k=0;k<16;++k) a = __fmaf_rn(w[r][k], y[k], a);
          a = wred(a);
          if (lane == r) xw[r0+r] = a + bv[r];
        }
      }
      gbar(flags, wg, (unsigned)(s+1), tid);
    }
  } else {
    // ---- d2 (H=2048) lag-2, fused output projection. wave owns i0..i0+3. ----
    const int gw = (wg-128)*4 + wave;  // 0..511
    const int i0 = gw*4;
    const int cb = lane*32;
    float w[3][4][32];                 // 384 VGPRs
    #pragma unroll
    for (int g=0; g<3; ++g)
      #pragma unroll
      for (int j=0; j<4; ++j)
        ld32(d2_Whh + (size_t)(g*2048 + i0 + j)*2048 + cb, w[g][j]);
    float bh[3][4];
    #pragma unroll
    for (int g=0; g<3; ++g)
      #pragma unroll
      for (int j=0; j<4; ++j) bh[g][j] = d2_bhh[g*2048 + i0 + j];
    float ow[4];
    #pragma unroll
    for (int j=0; j<4; ++j) ow[j] = out_W[i0+j];
    float* part = ws + OFF_PART + (size_t)(wg-128)*4096;
    for (int s=0; s<=T_STEPS+1; ++s){
      if (s >= 2){
        const int t = s-2;
        const float* hp  = hbuf + ((t+2)%3)*3072 + 1024;
        float*       hw  = hbuf + (t%3)*3072 + 1024;
        const float* xgp = xg4 + (t%3)*6144;
        float h[32]; ld32(hp + cb, h);
        float op = 0.f;
        #pragma unroll
        for (int j=0; j<4; ++j){
          float a0=0.f, a1=0.f, a2=0.f;
          #pragma unroll
          for (int k=0;k<32;++k){
            a0 = __fmaf_rn(w[0][j][k], h[k], a0);
            a1 = __fmaf_rn(w[1][j][k], h[k], a1);
            a2 = __fmaf_rn(w[2][j][k], h[k], a2);
          }
          const float hr = wred(a0), hz = wred(a1), hn = wred(a2);
          const float r = sigm (xgp[i0+j]       + hr + bh[0][j]);
          const float z = sigm (xgp[2048+i0+j]  + hz + bh[1][j]);
          const float n = tanhx(xgp[4096+i0+j]  + r*(hn + bh[2][j]));
          const float hnew = (1.f - z)*n + z*hp[i0+j];
          if (lane == 0) hw[i0+j] = hnew;
          op = __fmaf_rn(hnew, ow[j], op);
        }
        if (lane == 0) sPS[wave] = op;
        __syncthreads();
        if (tid == 0) part[t] = sPS[0]+sPS[1]+sPS[2]+sPS[3];
      }
      gbar(flags, wg, (unsigned)(s+1), tid);
    }
  }
}

__global__ void out_kernel(const float* __restrict__ out_b,
                           const float* __restrict__ ws, float* __restrict__ out){
  const int t = blockIdx.x*256 + threadIdx.x;
  float a = 0.f;
  for (int b=0; b<128; ++b) a += ws[OFF_PART + (size_t)b*4096 + t];
  out[t] = a + out_b[0];
}

extern "C" void kernel_launch(void* const* d_in, const int* in_sizes, int n_in,
                              void* d_out, int out_size, void* d_ws, size_t ws_size,
                              hipStream_t stream){
  const float* x       = (const float*)d_in[0];
  const float* e1_Wih  = (const float*)d_in[1];
  const float* e1_Whh  = (const float*)d_in[2];
  const float* e1_bih  = (const float*)d_in[3];
  const float* e1_bhh  = (const float*)d_in[4];
  const float* e2_Wih  = (const float*)d_in[5];
  const float* e2_Whh  = (const float*)d_in[6];
  const float* e2_bih  = (const float*)d_in[7];
  const float* e2_bhh  = (const float*)d_in[8];
  const float* d1_Wih  = (const float*)d_in[9];
  const float* d1_Whh  = (const float*)d_in[10];
  const float* d1_bih  = (const float*)d_in[11];
  const float* d1_bhh  = (const float*)d_in[12];
  const float* d2_Wih  = (const float*)d_in[13];
  const float* d2_Whh  = (const float*)d_in[14];
  const float* d2_bih  = (const float*)d_in[15];
  const float* d2_bhh  = (const float*)d_in[16];
  const float* out_W   = (const float*)d_in[17];
  const float* out_b   = (const float*)d_in[18];
  float* ws  = (float*)d_ws;
  float* out = (float*)d_out;

  hipLaunchKernelGGL(init_kernel, dim3((INIT_WORDS+255)/256), dim3(256), 0, stream,
                     (unsigned*)d_ws);
  hipLaunchKernelGGL(enc_kernel, dim3(256), dim3(256), 0, stream,
                     x, e1_Wih, e1_Whh, e1_bih, e1_bhh,
                     e2_Wih, e2_Whh, e2_bih, e2_bhh, ws);
  hipLaunchKernelGGL(xgd1_kernel, dim3(768), dim3(256), 0, stream,
                     d1_Wih, d1_bih, ws);
  hipLaunchKernelGGL(dec_kernel, dim3(256), dim3(256), 0, stream,
                     d1_Whh, d1_bhh, d2_Wih, d2_Whh, d2_bih, d2_bhh, out_W, ws);
  hipLaunchKernelGGL(out_kernel, dim3(16), dim3(256), 0, stream,
                     out_b, ws, out);
}

// Round 2
// 93685.449 us; speedup vs baseline: 3.1039x; 3.1039x over previous
//
#include <hip/hip_runtime.h>
#include <cstddef>

#define T_STEPS 4096

// ---- ws layout (32-bit word offsets) ----
#define OFF_FLAGS_E 0          // 256 flags, 16-word (64B) stride
#define OFF_FLAGS_D 4096       // 256 flags, 16-word stride
#define OFF_HBUF_E  8192       // 3*3072 f32  [slot][ e1 h (2048) | e2 h (1024) ]
#define OFF_HBUF_D  17408      // 3*3072 f32  [slot][ d1 h (1024) | d2 h (2048) ]
#define OFF_XG4     26624      // 3*6144 f32  d2 input gates, mod-3 slots
#define OFF_XGD1    45056      // 3072 f32    d1 constant input gates (incl bih)
#define OFF_PART    48128      // 128*4096 f32 per-wg output partials
#define INIT_WORDS  45056

#define DEV __device__ __forceinline__

DEV float sigm(float v){ return __fdividef(1.f, 1.f + __expf(-v)); }
DEV float tanhx(float v){ float e = __expf(2.f*v); return 1.f - __fdividef(2.f, e + 1.f); }

DEV float wred(float v){
  #pragma unroll
  for (int m = 32; m; m >>= 1) v += __shfl_xor(v, m, 64);
  return v;  // full sum in all 64 lanes
}

// ---- agent-scope (L3-coherent, L1/L2-bypassing) data movement ----
DEV void  sstore(float* p, float v){ __hip_atomic_store(p, v, __ATOMIC_RELAXED, __HIP_MEMORY_SCOPE_AGENT); }
DEV float sload (const float* p){ return __hip_atomic_load(p, __ATOMIC_RELAXED, __HIP_MEMORY_SCOPE_AGENT); }

DEV void ld32s(const float* p, float* d){
  #pragma unroll
  for (int i=0;i<32;++i) d[i] = sload(p+i);
}
DEV void ld16s(const float* p, float* d){
  #pragma unroll
  for (int i=0;i<16;++i) d[i] = sload(p+i);
}

// normal vector loads (weights, one-time)
DEV void ld32(const float* __restrict__ p, float* d){
  const float4* q = (const float4*)p;
  #pragma unroll
  for (int i=0;i<8;++i){ float4 v = q[i]; d[4*i]=v.x; d[4*i+1]=v.y; d[4*i+2]=v.z; d[4*i+3]=v.w; }
}
DEV void ld16(const float* __restrict__ p, float* d){
  const float4* q = (const float4*)p;
  #pragma unroll
  for (int i=0;i<4;++i){ float4 v = q[i]; d[4*i]=v.x; d[4*i+1]=v.y; d[4*i+2]=v.z; d[4*i+3]=v.w; }
}

// Distributed 256-wg barrier. All cross-wg data is written with agent-scope
// stores (visible at L3 once vmcnt drains, which __syncthreads does before
// s_barrier) — so NO threadfence / L2 writeback / invalidate is needed.
DEV void gbar(unsigned* flags, int wg, unsigned target, int tid){
  __syncthreads();                  // drains each wave's vmcnt; exec sync
  if (tid == 0)
    __hip_atomic_store(&flags[wg*16], target, __ATOMIC_RELAXED, __HIP_MEMORY_SCOPE_AGENT);
  if (tid < 64){                    // wave 0 polls; lane l covers 4 wgs
    bool ok;
    do {
      ok = true;
      #pragma unroll
      for (int j=0;j<4;++j){
        unsigned v = __hip_atomic_load(&flags[(tid + 64*j)*16], __ATOMIC_RELAXED, __HIP_MEMORY_SCOPE_AGENT);
        ok = ok && (v >= target);
      }
      if (!__all(ok)) __builtin_amdgcn_s_sleep(1);
      else break;
    } while (true);
  }
  __syncthreads();
}

__global__ void init_kernel(unsigned* ws){
  const int i = blockIdx.x*blockDim.x + threadIdx.x;
  if (i < INIT_WORDS) ws[i] = 0u;
}

// ================= ENCODER: e1 (128 wgs) + e2 lag-1 (128 wgs) =================
__global__ __launch_bounds__(256, 1) void enc_kernel(
    const float* __restrict__ x,
    const float* __restrict__ e1_Wih, const float* __restrict__ e1_Whh,
    const float* __restrict__ e1_bih, const float* __restrict__ e1_bhh,
    const float* __restrict__ e2_Wih, const float* __restrict__ e2_Whh,
    const float* __restrict__ e2_bih, const float* __restrict__ e2_bhh,
    float* ws)
{
  const int wg = blockIdx.x, tid = threadIdx.x;
  const int wave = tid >> 6, lane = tid & 63;
  float* hbuf = ws + OFF_HBUF_E;
  unsigned* flags = (unsigned*)ws + OFF_FLAGS_E;

  __shared__ float sW[4][12], sBi[4][12], sBh[4][12];

  if (wg < 128){
    // ---- role A: e1 (H=2048). wave owns i0..i0+3; lane owns 32 cols. ----
    const int gw = wg*4 + wave;          // 0..511
    const int i0 = gw*4;
    const int cb = lane*32;
    float w[3][4][32];                   // 384 VGPRs, resident all 4096 steps
    #pragma unroll
    for (int g=0; g<3; ++g)
      #pragma unroll
      for (int j=0; j<4; ++j)
        ld32(e1_Whh + (size_t)(g*2048 + i0 + j)*2048 + cb, w[g][j]);
    if (lane < 12){
      const int g = lane >> 2, j = lane & 3;
      const int row = g*2048 + i0 + j;
      sW[wave][lane]  = e1_Wih[row];
      sBi[wave][lane] = e1_bih[row];
      sBh[wave][lane] = e1_bhh[row];
    }
    __syncthreads();
    for (int s=0; s<=T_STEPS; ++s){
      if (s < T_STEPS){
        const int t = s;
        const float* hp = hbuf + ((t+2)%3)*3072;
        float*       hw = hbuf + (t%3)*3072;
        float h[32]; ld32s(hp + cb, h);
        float hpv[4];
        #pragma unroll
        for (int j=0;j<4;++j) hpv[j] = sload(hp + i0 + j);
        const float xt = x[t];
        float acc[3][4];
        #pragma unroll
        for (int g=0; g<3; ++g)
          #pragma unroll
          for (int j=0; j<4; ++j){
            float a = 0.f;
            #pragma unroll
            for (int k=0; k<32; ++k) a = __fmaf_rn(w[g][j][k], h[k], a);
            acc[g][j] = a;
          }
        #pragma unroll
        for (int j=0; j<4; ++j){
          const float hr = wred(acc[0][j]);
          const float hz = wred(acc[1][j]);
          const float hn = wred(acc[2][j]);
          const float r = sigm (__fmaf_rn(xt, sW[wave][j],    sBi[wave][j])    + hr + sBh[wave][j]);
          const float z = sigm (__fmaf_rn(xt, sW[wave][4+j],  sBi[wave][4+j])  + hz + sBh[wave][4+j]);
          const float n = tanhx(__fmaf_rn(xt, sW[wave][8+j],  sBi[wave][8+j])  + r*(hn + sBh[wave][8+j]));
          const float hnew = (1.f - z)*n + z*hpv[j];
          if (lane == 0) sstore(hw + i0 + j, hnew);
        }
      }
      gbar(flags, wg, (unsigned)(s+1), tid);
    }
  } else {
    // ---- role B: e2 (H=1024, K_in=2048) lag-1. wave owns i0..i0+1. ----
    const int gw = (wg-128)*4 + wave;    // 0..511
    const int i0 = gw*2;
    const int cb32 = lane*32, cb16 = lane*16;
    float wih[3][2][32], whh[3][2][16];  // 288 VGPRs
    #pragma unroll
    for (int g=0; g<3; ++g)
      #pragma unroll
      for (int j=0; j<2; ++j){
        ld32(e2_Wih + (size_t)(g*1024 + i0 + j)*2048 + cb32, wih[g][j]);
        ld16(e2_Whh + (size_t)(g*1024 + i0 + j)*1024 + cb16, whh[g][j]);
      }
    if (lane < 6){
      const int g = lane >> 1, j = lane & 1;
      const int row = g*1024 + i0 + j;
      sBi[wave][lane] = e2_bih[row];
      sBh[wave][lane] = e2_bhh[row];
    }
    __syncthreads();
    for (int s=0; s<=T_STEPS; ++s){
      if (s >= 1){
        const int t = s-1;
        const float* yp = hbuf + (t%3)*3072;            // ys1[t] (e1 section)
        const float* hp = hbuf + ((t+2)%3)*3072 + 2048; // own h_{t-1}
        float*       hw = hbuf + (t%3)*3072 + 2048;
        float y[32]; ld32s(yp + cb32, y);
        float h[16]; ld16s(hp + cb16, h);
        float hpv[2];
        #pragma unroll
        for (int j=0;j<2;++j) hpv[j] = sload(hp + i0 + j);
        #pragma unroll
        for (int j=0; j<2; ++j){
          float ar=0.f, az=0.f, axn=0.f, ahn=0.f;
          #pragma unroll
          for (int k=0;k<32;++k){
            ar  = __fmaf_rn(wih[0][j][k], y[k], ar);
            az  = __fmaf_rn(wih[1][j][k], y[k], az);
            axn = __fmaf_rn(wih[2][j][k], y[k], axn);
          }
          #pragma unroll
          for (int k=0;k<16;++k){
            ar  = __fmaf_rn(whh[0][j][k], h[k], ar);
            az  = __fmaf_rn(whh[1][j][k], h[k], az);
            ahn = __fmaf_rn(whh[2][j][k], h[k], ahn);
          }
          const float arr = wred(ar), azr = wred(az), axnr = wred(axn), ahnr = wred(ahn);
          const float r = sigm (arr + sBi[wave][j]   + sBh[wave][j]);
          const float z = sigm (azr + sBi[wave][2+j] + sBh[wave][2+j]);
          const float n = tanhx(axnr + sBi[wave][4+j] + r*(ahnr + sBh[wave][4+j]));
          const float hnew = (1.f - z)*n + z*hpv[j];
          if (lane == 0) sstore(hw + i0 + j, hnew);
        }
      }
      gbar(flags, wg, (unsigned)(s+1), tid);
    }
  }
}

// xgd1[row] = d1_Wih[row,:] . hT + d1_bih[row]  (hT = e2 h at t=4095, slot 0)
// Separate dispatch: kernel-boundary release/acquire gives coherence; normal loads.
__global__ void xgd1_kernel(const float* __restrict__ d1_Wih,
                            const float* __restrict__ d1_bih, float* ws){
  const int gw = blockIdx.x*4 + (threadIdx.x >> 6);  // row 0..3071
  const int lane = threadIdx.x & 63;
  const float* hT = ws + OFF_HBUF_E + 2048;          // slot 0, e2 section
  float h[16]; ld16(hT + lane*16, h);
  float wv[16]; ld16(d1_Wih + (size_t)gw*1024 + lane*16, wv);
  float a = 0.f;
  #pragma unroll
  for (int k=0;k<16;++k) a = __fmaf_rn(wv[k], h[k], a);
  a = wred(a);
  if (lane == 0) ws[OFF_XGD1 + gw] = a + d1_bih[gw];
}

// ====== DECODER: d1 (32 wgs) + d2-input GEMV lag-1 (96 wgs) + d2 lag-2 (128 wgs) ======
__global__ __launch_bounds__(256, 1) void dec_kernel(
    const float* __restrict__ d1_Whh, const float* __restrict__ d1_bhh,
    const float* __restrict__ d2_Wih, const float* __restrict__ d2_Whh,
    const float* __restrict__ d2_bih, const float* __restrict__ d2_bhh,
    const float* __restrict__ out_W,
    float* ws)
{
  const int wg = blockIdx.x, tid = threadIdx.x;
  const int wave = tid >> 6, lane = tid & 63;
  float* hbuf = ws + OFF_HBUF_D;
  float* xg4  = ws + OFF_XG4;
  unsigned* flags = (unsigned*)ws + OFF_FLAGS_D;
  __shared__ float sPS[4];

  if (wg < 32){
    // ---- d1 (H=1024), constant input gates. wave owns i0..i0+7. ----
    const int gw = wg*4 + wave;       // 0..127
    const int i0 = gw*8;
    const int cb = lane*16;
    float w[3][8][16];                // 384 VGPRs
    #pragma unroll
    for (int g=0; g<3; ++g)
      #pragma unroll
      for (int j=0; j<8; ++j)
        ld16(d1_Whh + (size_t)(g*1024 + i0 + j)*1024 + cb, w[g][j]);
    float cr[8], cz[8], cxn[8], cbn[8];
    const float* xgc = ws + OFF_XGD1;
    #pragma unroll
    for (int j=0; j<8; ++j){
      cr[j]  = xgc[i0+j]      + d1_bhh[i0+j];
      cz[j]  = xgc[1024+i0+j] + d1_bhh[1024+i0+j];
      cxn[j] = xgc[2048+i0+j];
      cbn[j] = d1_bhh[2048+i0+j];
    }
    for (int s=0; s<=T_STEPS+1; ++s){
      if (s < T_STEPS){
        const int t = s;
        const float* hp = hbuf + ((t+2)%3)*3072;
        float*       hw = hbuf + (t%3)*3072;
        float h[16]; ld16s(hp + cb, h);
        float hpv[8];
        #pragma unroll
        for (int j=0;j<8;++j) hpv[j] = sload(hp + i0 + j);
        #pragma unroll
        for (int j=0; j<8; ++j){
          float a0=0.f, a1=0.f, a2=0.f;
          #pragma unroll
          for (int k=0;k<16;++k){
            a0 = __fmaf_rn(w[0][j][k], h[k], a0);
            a1 = __fmaf_rn(w[1][j][k], h[k], a1);
            a2 = __fmaf_rn(w[2][j][k], h[k], a2);
          }
          const float hr = wred(a0), hz = wred(a1), hn = wred(a2);
          const float r = sigm (cr[j] + hr);
          const float z = sigm (cz[j] + hz);
          const float n = tanhx(cxn[j] + r*(hn + cbn[j]));
          const float hnew = (1.f - z)*n + z*hpv[j];
          if (lane == 0) sstore(hw + i0 + j, hnew);
        }
      }
      gbar(flags, wg, (unsigned)(s+1), tid);
    }
  } else if (wg < 128){
    // ---- d2 input GEMV: xg4[t] = d2_Wih @ ys2[t] + bih, lag-1. wave owns 16 rows. ----
    const int gw = (wg-32)*4 + wave;   // 0..383
    const int r0 = gw*16;
    const int cb = lane*16;
    float w[16][16];                   // 256 VGPRs
    #pragma unroll
    for (int r=0; r<16; ++r)
      ld16(d2_Wih + (size_t)(r0 + r)*1024 + cb, w[r]);
    float bv[16];
    #pragma unroll
    for (int r=0; r<16; ++r) bv[r] = d2_bih[r0+r];
    for (int s=0; s<=T_STEPS+1; ++s){
      if (s >= 1 && s <= T_STEPS){
        const int t = s-1;
        const float* yp = hbuf + (t%3)*3072;   // ys2[t] (d1 section)
        float*       xw = xg4 + (t%3)*6144;
        float y[16]; ld16s(yp + cb, y);
        #pragma unroll
        for (int r=0; r<16; ++r){
          float a = 0.f;
          #pragma unroll
          for (int k=0;k<16;++k) a = __fmaf_rn(w[r][k], y[k], a);
          a = wred(a);
          if (lane == r) sstore(xw + r0 + r, a + bv[r]);
        }
      }
      gbar(flags, wg, (unsigned)(s+1), tid);
    }
  } else {
    // ---- d2 (H=2048) lag-2, fused output projection. wave owns i0..i0+3. ----
    const int gw = (wg-128)*4 + wave;  // 0..511
    const int i0 = gw*4;
    const int cb = lane*32;
    float w[3][4][32];                 // 384 VGPRs
    #pragma unroll
    for (int g=0; g<3; ++g)
      #pragma unroll
      for (int j=0; j<4; ++j)
        ld32(d2_Whh + (size_t)(g*2048 + i0 + j)*2048 + cb, w[g][j]);
    float bh[3][4];
    #pragma unroll
    for (int g=0; g<3; ++g)
      #pragma unroll
      for (int j=0; j<4; ++j) bh[g][j] = d2_bhh[g*2048 + i0 + j];
    float ow[4];
    #pragma unroll
    for (int j=0; j<4; ++j) ow[j] = out_W[i0+j];
    float* part = ws + OFF_PART + (size_t)(wg-128)*4096;
    for (int s=0; s<=T_STEPS+1; ++s){
      if (s >= 2){
        const int t = s-2;
        const float* hp  = hbuf + ((t+2)%3)*3072 + 1024;
        float*       hw  = hbuf + (t%3)*3072 + 1024;
        const float* xgp = xg4 + (t%3)*6144;
        float h[32]; ld32s(hp + cb, h);
        float hpv[4], xr4[4], xz4[4], xn4[4];
        #pragma unroll
        for (int j=0;j<4;++j){
          hpv[j] = sload(hp + i0 + j);
          xr4[j] = sload(xgp + i0 + j);
          xz4[j] = sload(xgp + 2048 + i0 + j);
          xn4[j] = sload(xgp + 4096 + i0 + j);
        }
        float op = 0.f;
        #pragma unroll
        for (int j=0; j<4; ++j){
          float a0=0.f, a1=0.f, a2=0.f;
          #pragma unroll
          for (int k=0;k<32;++k){
            a0 = __fmaf_rn(w[0][j][k], h[k], a0);
            a1 = __fmaf_rn(w[1][j][k], h[k], a1);
            a2 = __fmaf_rn(w[2][j][k], h[k], a2);
          }
          const float hr = wred(a0), hz = wred(a1), hn = wred(a2);
          const float r = sigm (xr4[j] + hr + bh[0][j]);
          const float z = sigm (xz4[j] + hz + bh[1][j]);
          const float n = tanhx(xn4[j] + r*(hn + bh[2][j]));
          const float hnew = (1.f - z)*n + z*hpv[j];
          if (lane == 0) sstore(hw + i0 + j, hnew);
          op = __fmaf_rn(hnew, ow[j], op);
        }
        if (lane == 0) sPS[wave] = op;
        __syncthreads();
        if (tid == 0) part[t] = sPS[0]+sPS[1]+sPS[2]+sPS[3];
        __syncthreads();
      }
      gbar(flags, wg, (unsigned)(s+1), tid);
    }
  }
}

__global__ void out_kernel(const float* __restrict__ out_b,
                           const float* __restrict__ ws, float* __restrict__ out){
  const int t = blockIdx.x*256 + threadIdx.x;
  float a = 0.f;
  for (int b=0; b<128; ++b) a += ws[OFF_PART + (size_t)b*4096 + t];
  out[t] = a + out_b[0];
}

extern "C" void kernel_launch(void* const* d_in, const int* in_sizes, int n_in,
                              void* d_out, int out_size, void* d_ws, size_t ws_size,
                              hipStream_t stream){
  const float* x       = (const float*)d_in[0];
  const float* e1_Wih  = (const float*)d_in[1];
  const float* e1_Whh  = (const float*)d_in[2];
  const float* e1_bih  = (const float*)d_in[3];
  const float* e1_bhh  = (const float*)d_in[4];
  const float* e2_Wih  = (const float*)d_in[5];
  const float* e2_Whh  = (const float*)d_in[6];
  const float* e2_bih  = (const float*)d_in[7];
  const float* e2_bhh  = (const float*)d_in[8];
  const float* d1_Wih  = (const float*)d_in[9];
  const float* d1_Whh  = (const float*)d_in[10];
  const float* d1_bih  = (const float*)d_in[11];
  const float* d1_bhh  = (const float*)d_in[12];
  const float* d2_Wih  = (const float*)d_in[13];
  const float* d2_Whh  = (const float*)d_in[14];
  const float* d2_bih  = (const float*)d_in[15];
  const float* d2_bhh  = (const float*)d_in[16];
  const float* out_W   = (const float*)d_in[17];
  const float* out_b   = (const float*)d_in[18];
  float* ws  = (float*)d_ws;
  float* out = (float*)d_out;

  hipLaunchKernelGGL(init_kernel, dim3((INIT_WORDS+255)/256), dim3(256), 0, stream,
                     (unsigned*)d_ws);
  hipLaunchKernelGGL(enc_kernel, dim3(256), dim3(256), 0, stream,
                     x, e1_Wih, e1_Whh, e1_bih, e1_bhh,
                     e2_Wih, e2_Whh, e2_bih, e2_bhh, ws);
  hipLaunchKernelGGL(xgd1_kernel, dim3(768), dim3(256), 0, stream,
                     d1_Wih, d1_bih, ws);
  hipLaunchKernelGGL(dec_kernel, dim3(256), dim3(256), 0, stream,
                     d1_Whh, d1_bhh, d2_Wih, d2_Whh, d2_bih, d2_bhh, out_W, ws);
  hipLaunchKernelGGL(out_kernel, dim3(16), dim3(256), 0, stream,
                     out_b, ws, out);
}

// Round 4
// 62118.054 us; speedup vs baseline: 4.6812x; 1.5082x over previous
//
#include <hip/hip_runtime.h>
#include <cstddef>

#define T_STEPS 4096

typedef float    v4f __attribute__((ext_vector_type(4)));
typedef unsigned v4u __attribute__((ext_vector_type(4)));

// ---- ws layout (32-bit word offsets) ----
#define OFF_FLAGS_E 0          // 256 u32, contiguous (16 cache lines)
#define OFF_FLAGS_D 256        // 256 u32
#define OFF_HBUF_E  512        // 3*3072 f32  [slot][ e1 h (2048) | e2 h (1024) ]
#define OFF_HBUF_D  9728       // 3*3072 f32  [slot][ d1 h (1024) | d2 h (2048) ]
#define OFF_XG4     18944      // 3*6144 f32  d2 input gates, mod-3 slots
#define OFF_XGD1    37376      // 3072 f32    d1 constant input gates (incl bih)
#define OFF_PART    40448      // 128*4096 f32 per-wg output partials
#define INIT_WORDS  40448

#define DEV __device__ __forceinline__

DEV float sigm(float v){ return __fdividef(1.f, 1.f + __expf(-v)); }
DEV float tanhx(float v){ float e = __expf(2.f*v); return 1.f - __fdividef(2.f, e + 1.f); }

DEV float wred(float v){
  #pragma unroll
  for (int m = 32; m; m >>= 1) v += __shfl_xor(v, m, 64);
  return v;
}

// scalar agent-scope (bypass non-coherent L1/L2, hit L3)
DEV void  sstore(float* p, float v){ __hip_atomic_store(p, v, __ATOMIC_RELAXED, __HIP_MEMORY_SCOPE_AGENT); }
DEV float sload (const float* p){ return __hip_atomic_load(p, __ATOMIC_RELAXED, __HIP_MEMORY_SCOPE_AGENT); }

// vector scoped loads (sc0 sc1 = bypass L1/L2; data travels via L3)
DEV v4f ldx4s(const float* p){
  v4f a;
  asm volatile("global_load_dwordx4 %0, %1, off sc0 sc1\n\ts_waitcnt vmcnt(0)"
               : "=v"(a) : "v"(p) : "memory");
  return a;
}
DEV void ldx8s(const float* p, v4f* a, v4f* b){
  asm volatile("global_load_dwordx4 %0, %2, off sc0 sc1\n\t"
               "global_load_dwordx4 %1, %2, off offset:16 sc0 sc1\n\t"
               "s_waitcnt vmcnt(0)"
               : "=v"(*a), "=v"(*b) : "v"(p) : "memory");
}
DEV v4u ldx4su(const unsigned* p){
  v4u a;
  asm volatile("global_load_dwordx4 %0, %1, off sc0 sc1\n\ts_waitcnt vmcnt(0)"
               : "=v"(a) : "v"(p) : "memory");
  return a;
}

// pin a value into a VGPR as an opaque (non-rematerializable) live range
#define PIN1(x) asm volatile("" : "+v"(x))

// Distributed 256-wg barrier: contiguous flags (16 lines), dwordx4 poll sweep.
DEV void gbar(unsigned* flags, int wg, unsigned target, int tid){
  __syncthreads();                  // drains vmcnt (scoped data stores reach L3)
  if (tid == 0)
    __hip_atomic_store(&flags[wg], target, __ATOMIC_RELAXED, __HIP_MEMORY_SCOPE_AGENT);
  if (tid < 64){
    const unsigned* fp = flags + tid*4;
    for (;;){
      v4u v = ldx4su(fp);
      unsigned m0 = v.x < v.y ? v.x : v.y;
      unsigned m1 = v.z < v.w ? v.z : v.w;
      unsigned m  = m0 < m1 ? m0 : m1;
      if (__all(m >= target)) break;
      __builtin_amdgcn_s_sleep(2);
    }
  }
  __syncthreads();
}

__global__ void init_kernel(unsigned* ws){
  const int i = blockIdx.x*blockDim.x + threadIdx.x;
  if (i < INIT_WORDS) ws[i] = 0u;
}

// ================= ENCODER: e1 (128 wgs) + e2 lag-1 (128 wgs) =================
__global__ __launch_bounds__(256, 1) __attribute__((amdgpu_waves_per_eu(1,1)))
void enc_kernel(
    const float* __restrict__ x,
    const float* __restrict__ e1_Wih, const float* __restrict__ e1_Whh,
    const float* __restrict__ e1_bih, const float* __restrict__ e1_bhh,
    const float* __restrict__ e2_Wih, const float* __restrict__ e2_Whh,
    const float* __restrict__ e2_bih, const float* __restrict__ e2_bhh,
    float* ws)
{
  const int wg = blockIdx.x, tid = threadIdx.x;
  const int wave = tid >> 6, lane = tid & 63;
  float* hbuf = ws + OFF_HBUF_E;
  unsigned* flags = (unsigned*)ws + OFF_FLAGS_E;

  __shared__ __align__(16) float sh[3072];
  __shared__ float sW[4][12], sBi[4][12], sBh[4][12];

  if (wg < 128){
    // ---- e1 (H=2048). wave owns rows i0..i0+3; lane owns cols lane+64c. ----
    const int gw = wg*4 + wave;          // 0..511
    const int i0 = gw*4;
    float w[3][4][32];                   // 384 VGPRs, pinned resident
    #pragma unroll
    for (int g=0; g<3; ++g)
      #pragma unroll
      for (int j=0; j<4; ++j)
        #pragma unroll
        for (int c=0; c<32; ++c){
          w[g][j][c] = e1_Whh[(size_t)(g*2048 + i0 + j)*2048 + c*64 + lane];
          PIN1(w[g][j][c]);
        }
    if (lane < 12){
      const int g = lane >> 2, j = lane & 3;
      const int row = g*2048 + i0 + j;
      sW[wave][lane]  = e1_Wih[row];
      sBi[wave][lane] = e1_bih[row];
      sBh[wave][lane] = e1_bhh[row];
    }
    __syncthreads();
    for (int s=0; s<=T_STEPS; ++s){
      if (s < T_STEPS){
        const int t = s;
        const float* hp = hbuf + ((t+2)%3)*3072;
        float*       hw = hbuf + (t%3)*3072;
        // stage h (2048 f32) into LDS: 8 floats/thread, scoped dwordx4 pair
        { v4f a, b; ldx8s(hp + tid*8, &a, &b);
          *(v4f*)&sh[tid*8] = a; *(v4f*)&sh[tid*8+4] = b; }
        __syncthreads();
        float hpv[4];
        #pragma unroll
        for (int j=0;j<4;++j) hpv[j] = sh[i0+j];   // LDS broadcast
        const float xt = x[t];
        float acc[3][4];
        #pragma unroll
        for (int g=0;g<3;++g)
          #pragma unroll
          for (int j=0;j<4;++j) acc[g][j] = 0.f;
        #pragma unroll
        for (int cc=0; cc<4; ++cc){
          float hh[8];
          #pragma unroll
          for (int u=0;u<8;++u) hh[u] = sh[(cc*8+u)*64 + lane];
          #pragma unroll
          for (int g=0; g<3; ++g)
            #pragma unroll
            for (int j=0; j<4; ++j)
              #pragma unroll
              for (int u=0;u<8;++u)
                acc[g][j] = __fmaf_rn(w[g][j][cc*8+u], hh[u], acc[g][j]);
        }
        #pragma unroll
        for (int j=0; j<4; ++j){
          const float hr = wred(acc[0][j]);
          const float hz = wred(acc[1][j]);
          const float hn = wred(acc[2][j]);
          const float r = sigm (__fmaf_rn(xt, sW[wave][j],    sBi[wave][j])    + hr + sBh[wave][j]);
          const float z = sigm (__fmaf_rn(xt, sW[wave][4+j],  sBi[wave][4+j])  + hz + sBh[wave][4+j]);
          const float n = tanhx(__fmaf_rn(xt, sW[wave][8+j],  sBi[wave][8+j])  + r*(hn + sBh[wave][8+j]));
          const float hnew = (1.f - z)*n + z*hpv[j];
          if (lane == 0) sstore(hw + i0 + j, hnew);
        }
      }
      gbar(flags, wg, (unsigned)(s+1), tid);
    }
  } else {
    // ---- e2 (H=1024, Kin=2048) lag-1. wave owns rows i0..i0+1. ----
    const int gw = (wg-128)*4 + wave;    // 0..511
    const int i0 = gw*2;
    float wih[3][2][32], whh[3][2][16];  // 288 VGPRs, pinned
    #pragma unroll
    for (int g=0; g<3; ++g)
      #pragma unroll
      for (int j=0; j<2; ++j){
        #pragma unroll
        for (int c=0; c<32; ++c){
          wih[g][j][c] = e2_Wih[(size_t)(g*1024 + i0 + j)*2048 + c*64 + lane];
          PIN1(wih[g][j][c]);
        }
        #pragma unroll
        for (int c=0; c<16; ++c){
          whh[g][j][c] = e2_Whh[(size_t)(g*1024 + i0 + j)*1024 + c*64 + lane];
          PIN1(whh[g][j][c]);
        }
      }
    if (lane < 6){
      const int g = lane >> 1, j = lane & 1;
      const int row = g*1024 + i0 + j;
      sBi[wave][lane] = e2_bih[row];
      sBh[wave][lane] = e2_bhh[row];
    }
    __syncthreads();
    for (int s=0; s<=T_STEPS; ++s){
      if (s >= 1){
        const int t = s-1;
        const float* yp  = hbuf + (t%3)*3072;            // ys1[t]
        const float* hp2 = hbuf + ((t+2)%3)*3072 + 2048; // own h_{t-1}
        float*       hw  = hbuf + (t%3)*3072 + 2048;
        { v4f a, b; ldx8s(yp + tid*8, &a, &b);
          *(v4f*)&sh[tid*8] = a; *(v4f*)&sh[tid*8+4] = b; }
        { v4f c4 = ldx4s(hp2 + tid*4);
          *(v4f*)&sh[2048 + tid*4] = c4; }
        __syncthreads();
        float hpv[2];
        #pragma unroll
        for (int j=0;j<2;++j) hpv[j] = sh[2048 + i0 + j];
        float ar[2]={0,0}, az[2]={0,0}, axn[2]={0,0}, ahn[2]={0,0};
        #pragma unroll
        for (int cc=0; cc<4; ++cc){
          float yy[8];
          #pragma unroll
          for (int u=0;u<8;++u) yy[u] = sh[(cc*8+u)*64 + lane];
          #pragma unroll
          for (int j=0;j<2;++j)
            #pragma unroll
            for (int u=0;u<8;++u){
              ar[j]  = __fmaf_rn(wih[0][j][cc*8+u], yy[u], ar[j]);
              az[j]  = __fmaf_rn(wih[1][j][cc*8+u], yy[u], az[j]);
              axn[j] = __fmaf_rn(wih[2][j][cc*8+u], yy[u], axn[j]);
            }
        }
        #pragma unroll
        for (int cc=0; cc<2; ++cc){
          float hh[8];
          #pragma unroll
          for (int u=0;u<8;++u) hh[u] = sh[2048 + (cc*8+u)*64 + lane];
          #pragma unroll
          for (int j=0;j<2;++j)
            #pragma unroll
            for (int u=0;u<8;++u){
              ar[j]  = __fmaf_rn(whh[0][j][cc*8+u], hh[u], ar[j]);
              az[j]  = __fmaf_rn(whh[1][j][cc*8+u], hh[u], az[j]);
              ahn[j] = __fmaf_rn(whh[2][j][cc*8+u], hh[u], ahn[j]);
            }
        }
        #pragma unroll
        for (int j=0; j<2; ++j){
          const float arr = wred(ar[j]), azr = wred(az[j]);
          const float axnr = wred(axn[j]), ahnr = wred(ahn[j]);
          const float r = sigm (arr + sBi[wave][j]   + sBh[wave][j]);
          const float z = sigm (azr + sBi[wave][2+j] + sBh[wave][2+j]);
          const float n = tanhx(axnr + sBi[wave][4+j] + r*(ahnr + sBh[wave][4+j]));
          const float hnew = (1.f - z)*n + z*hpv[j];
          if (lane == 0) sstore(hw + i0 + j, hnew);
        }
      }
      gbar(flags, wg, (unsigned)(s+1), tid);
    }
  }
}

// xgd1[row] = d1_Wih[row,:] . hT + d1_bih[row]  (hT = e2 h at t=4095, slot 0)
__global__ void xgd1_kernel(const float* __restrict__ d1_Wih,
                            const float* __restrict__ d1_bih, float* ws){
  const int gw = blockIdx.x*4 + (threadIdx.x >> 6);  // row 0..3071
  const int lane = threadIdx.x & 63;
  const float* hT = ws + OFF_HBUF_E + 2048;          // slot 0, e2 section
  float a = 0.f;
  #pragma unroll
  for (int c=0;c<16;++c)
    a = __fmaf_rn(d1_Wih[(size_t)gw*1024 + c*64 + lane], hT[c*64 + lane], a);
  a = wred(a);
  if (lane == 0) ws[OFF_XGD1 + gw] = a + d1_bih[gw];
}

// ====== DECODER: d1 (32 wgs) + d2-input GEMV lag-1 (96 wgs) + d2 lag-2 (128 wgs) ======
__global__ __launch_bounds__(256, 1) __attribute__((amdgpu_waves_per_eu(1,1)))
void dec_kernel(
    const float* __restrict__ d1_Whh, const float* __restrict__ d1_bhh,
    const float* __restrict__ d2_Wih, const float* __restrict__ d2_Whh,
    const float* __restrict__ d2_bih, const float* __restrict__ d2_bhh,
    const float* __restrict__ out_W,
    float* ws)
{
  const int wg = blockIdx.x, tid = threadIdx.x;
  const int wave = tid >> 6, lane = tid & 63;
  float* hbuf = ws + OFF_HBUF_D;
  float* xg4  = ws + OFF_XG4;
  unsigned* flags = (unsigned*)ws + OFF_FLAGS_D;
  __shared__ __align__(16) float sh[2048];
  __shared__ float sPS[4];

  if (wg < 32){
    // ---- d1 (H=1024), constant input gates. wave owns rows i0..i0+7. ----
    const int gw = wg*4 + wave;       // 0..127
    const int i0 = gw*8;
    float w[3][8][16];                // 384 VGPRs, pinned
    #pragma unroll
    for (int g=0; g<3; ++g)
      #pragma unroll
      for (int j=0; j<8; ++j)
        #pragma unroll
        for (int c=0; c<16; ++c){
          w[g][j][c] = d1_Whh[(size_t)(g*1024 + i0 + j)*1024 + c*64 + lane];
          PIN1(w[g][j][c]);
        }
    float cr[8], cz[8], cxn[8], cbn[8];
    const float* xgc = ws + OFF_XGD1;
    #pragma unroll
    for (int j=0; j<8; ++j){
      cr[j]  = xgc[i0+j]      + d1_bhh[i0+j];
      cz[j]  = xgc[1024+i0+j] + d1_bhh[1024+i0+j];
      cxn[j] = xgc[2048+i0+j];
      cbn[j] = d1_bhh[2048+i0+j];
    }
    for (int s=0; s<=T_STEPS+1; ++s){
      if (s < T_STEPS){
        const int t = s;
        const float* hp = hbuf + ((t+2)%3)*3072;
        float*       hw = hbuf + (t%3)*3072;
        { v4f c4 = ldx4s(hp + tid*4); *(v4f*)&sh[tid*4] = c4; }
        __syncthreads();
        float hpv[8];
        #pragma unroll
        for (int j=0;j<8;++j) hpv[j] = sh[i0+j];
        float a0[8], a1[8], a2[8];
        #pragma unroll
        for (int j=0;j<8;++j){ a0[j]=0.f; a1[j]=0.f; a2[j]=0.f; }
        #pragma unroll
        for (int cc=0; cc<2; ++cc){
          float hh[8];
          #pragma unroll
          for (int u=0;u<8;++u) hh[u] = sh[(cc*8+u)*64 + lane];
          #pragma unroll
          for (int j=0;j<8;++j)
            #pragma unroll
            for (int u=0;u<8;++u){
              a0[j] = __fmaf_rn(w[0][j][cc*8+u], hh[u], a0[j]);
              a1[j] = __fmaf_rn(w[1][j][cc*8+u], hh[u], a1[j]);
              a2[j] = __fmaf_rn(w[2][j][cc*8+u], hh[u], a2[j]);
            }
        }
        #pragma unroll
        for (int j=0; j<8; ++j){
          const float hr = wred(a0[j]), hz = wred(a1[j]), hn = wred(a2[j]);
          const float r = sigm (cr[j] + hr);
          const float z = sigm (cz[j] + hz);
          const float n = tanhx(cxn[j] + r*(hn + cbn[j]));
          const float hnew = (1.f - z)*n + z*hpv[j];
          if (lane == 0) sstore(hw + i0 + j, hnew);
        }
      }
      gbar(flags, wg, (unsigned)(s+1), tid);
    }
  } else if (wg < 128){
    // ---- d2 input GEMV: xg4[t] = d2_Wih @ ys2[t] + bih, lag-1. wave owns 16 rows. ----
    const int gw = (wg-32)*4 + wave;   // 0..383
    const int r0 = gw*16;
    float w[16][16];                   // 256 VGPRs, pinned
    #pragma unroll
    for (int r=0; r<16; ++r)
      #pragma unroll
      for (int c=0; c<16; ++c){
        w[r][c] = d2_Wih[(size_t)(r0 + r)*1024 + c*64 + lane];
        PIN1(w[r][c]);
      }
    float bv[16];
    #pragma unroll
    for (int r=0; r<16; ++r) bv[r] = d2_bih[r0+r];
    for (int s=0; s<=T_STEPS+1; ++s){
      if (s >= 1 && s <= T_STEPS){
        const int t = s-1;
        const float* yp = hbuf + (t%3)*3072;   // ys2[t] (d1 section)
        float*       xw = xg4 + (t%3)*6144;
        { v4f c4 = ldx4s(yp + tid*4); *(v4f*)&sh[tid*4] = c4; }
        __syncthreads();
        float acc[16];
        #pragma unroll
        for (int r=0;r<16;++r) acc[r]=0.f;
        #pragma unroll
        for (int cc=0; cc<2; ++cc){
          float yy[8];
          #pragma unroll
          for (int u=0;u<8;++u) yy[u] = sh[(cc*8+u)*64 + lane];
          #pragma unroll
          for (int r=0;r<16;++r)
            #pragma unroll
            for (int u=0;u<8;++u)
              acc[r] = __fmaf_rn(w[r][cc*8+u], yy[u], acc[r]);
        }
        #pragma unroll
        for (int r=0; r<16; ++r){
          const float a = wred(acc[r]);
          if (lane == r) sstore(xw + r0 + r, a + bv[r]);
        }
      }
      gbar(flags, wg, (unsigned)(s+1), tid);
    }
  } else {
    // ---- d2 (H=2048) lag-2, fused output projection. wave owns rows i0..i0+3. ----
    const int gw = (wg-128)*4 + wave;  // 0..511
    const int i0 = gw*4;
    float w[3][4][32];                 // 384 VGPRs, pinned
    #pragma unroll
    for (int g=0; g<3; ++g)
      #pragma unroll
      for (int j=0; j<4; ++j)
        #pragma unroll
        for (int c=0; c<32; ++c){
          w[g][j][c] = d2_Whh[(size_t)(g*2048 + i0 + j)*2048 + c*64 + lane];
          PIN1(w[g][j][c]);
        }
    float bh[3][4];
    #pragma unroll
    for (int g=0; g<3; ++g)
      #pragma unroll
      for (int j=0; j<4; ++j) bh[g][j] = d2_bhh[g*2048 + i0 + j];
    float ow[4];
    #pragma unroll
    for (int j=0; j<4; ++j) ow[j] = out_W[i0+j];
    float* part = ws + OFF_PART + (size_t)(wg-128)*4096;
    for (int s=0; s<=T_STEPS+1; ++s){
      if (s >= 2){
        const int t = s-2;
        const float* hp  = hbuf + ((t+2)%3)*3072 + 1024;
        float*       hw  = hbuf + (t%3)*3072 + 1024;
        const float* xgp = xg4 + (t%3)*6144;
        { v4f a, b; ldx8s(hp + tid*8, &a, &b);
          *(v4f*)&sh[tid*8] = a; *(v4f*)&sh[tid*8+4] = b; }
        __syncthreads();
        float hpv[4], xr4[4], xz4[4], xn4[4];
        #pragma unroll
        for (int j=0;j<4;++j){
          hpv[j] = sh[i0+j];
          xr4[j] = sload(xgp + i0 + j);          // wave-uniform address
          xz4[j] = sload(xgp + 2048 + i0 + j);
          xn4[j] = sload(xgp + 4096 + i0 + j);
        }
        float a0[4], a1[4], a2[4];
        #pragma unroll
        for (int j=0;j<4;++j){ a0[j]=0.f; a1[j]=0.f; a2[j]=0.f; }
        #pragma unroll
        for (int cc=0; cc<4; ++cc){
          float hh[8];
          #pragma unroll
          for (int u=0;u<8;++u) hh[u] = sh[(cc*8+u)*64 + lane];
          #pragma unroll
          for (int j=0;j<4;++j)
            #pragma unroll
            for (int u=0;u<8;++u){
              a0[j] = __fmaf_rn(w[0][j][cc*8+u], hh[u], a0[j]);
              a1[j] = __fmaf_rn(w[1][j][cc*8+u], hh[u], a1[j]);
              a2[j] = __fmaf_rn(w[2][j][cc*8+u], hh[u], a2[j]);
            }
        }
        float op = 0.f;
        #pragma unroll
        for (int j=0; j<4; ++j){
          const float hr = wred(a0[j]), hz = wred(a1[j]), hn = wred(a2[j]);
          const float r = sigm (xr4[j] + hr + bh[0][j]);
          const float z = sigm (xz4[j] + hz + bh[1][j]);
          const float n = tanhx(xn4[j] + r*(hn + bh[2][j]));
          const float hnew = (1.f - z)*n + z*hpv[j];
          if (lane == 0) sstore(hw + i0 + j, hnew);
          op = __fmaf_rn(hnew, ow[j], op);
        }
        if (lane == 0) sPS[wave] = op;
        __syncthreads();
        if (tid == 0) part[t] = sPS[0]+sPS[1]+sPS[2]+sPS[3];
        __syncthreads();
      }
      gbar(flags, wg, (unsigned)(s+1), tid);
    }
  }
}

__global__ void out_kernel(const float* __restrict__ out_b,
                           const float* __restrict__ ws, float* __restrict__ out){
  const int t = blockIdx.x*256 + threadIdx.x;
  float a = 0.f;
  for (int b=0; b<128; ++b) a += ws[OFF_PART + (size_t)b*4096 + t];
  out[t] = a + out_b[0];
}

extern "C" void kernel_launch(void* const* d_in, const int* in_sizes, int n_in,
                              void* d_out, int out_size, void* d_ws, size_t ws_size,
                              hipStream_t stream){
  const float* x       = (const float*)d_in[0];
  const float* e1_Wih  = (const float*)d_in[1];
  const float* e1_Whh  = (const float*)d_in[2];
  const float* e1_bih  = (const float*)d_in[3];
  const float* e1_bhh  = (const float*)d_in[4];
  const float* e2_Wih  = (const float*)d_in[5];
  const float* e2_Whh  = (const float*)d_in[6];
  const float* e2_bih  = (const float*)d_in[7];
  const float* e2_bhh  = (const float*)d_in[8];
  const float* d1_Wih  = (const float*)d_in[9];
  const float* d1_Whh  = (const float*)d_in[10];
  const float* d1_bih  = (const float*)d_in[11];
  const float* d1_bhh  = (const float*)d_in[12];
  const float* d2_Wih  = (const float*)d_in[13];
  const float* d2_Whh  = (const float*)d_in[14];
  const float* d2_bih  = (const float*)d_in[15];
  const float* d2_bhh  = (const float*)d_in[16];
  const float* out_W   = (const float*)d_in[17];
  const float* out_b   = (const float*)d_in[18];
  float* ws  = (float*)d_ws;
  float* out = (float*)d_out;

  hipLaunchKernelGGL(init_kernel, dim3((INIT_WORDS+255)/256), dim3(256), 0, stream,
                     (unsigned*)d_ws);
  hipLaunchKernelGGL(enc_kernel, dim3(256), dim3(256), 0, stream,
                     x, e1_Wih, e1_Whh, e1_bih, e1_bhh,
                     e2_Wih, e2_Whh, e2_bih, e2_bhh, ws);
  hipLaunchKernelGGL(xgd1_kernel, dim3(768), dim3(256), 0, stream,
                     d1_Wih, d1_bih, ws);
  hipLaunchKernelGGL(dec_kernel, dim3(256), dim3(256), 0, stream,
                     d1_Whh, d1_bhh, d2_Wih, d2_Whh, d2_bih, d2_bhh, out_W, ws);
  hipLaunchKernelGGL(out_kernel, dim3(16), dim3(256), 0, stream,
                     out_b, ws, out);
}